// Round 12
// baseline (505.000 us; speedup 1.0000x reference)
//
#include <hip/hip_runtime.h>
#include <hip/hip_bf16.h>

// ---------------------------------------------------------------------------
// MonotonicAlignmentSearch R24: R22 base (best, 150.6us) + inline softmax.
// Logits blocks now cover the FULL h range (64 blocks x 4 bt-rows x 512 a,
// 256 hq iterations) so each block holds complete logit rows -> softmax is
// done in-block and written straight to out. The lp partial buffer and the
// 256 softmax blocks of combine_k are deleted (combine = 32 conv3 blocks).
// Conv structure reverted to R22's proven 16-chan tiles (R23's 32-chan
// variant regressed). B=2, TT=128, TA=512, H=1024.
// ---------------------------------------------------------------------------

typedef __bf16 bf16_t;
typedef __bf16 bf16x8 __attribute__((ext_vector_type(8)));
typedef __bf16 bf16x4 __attribute__((ext_vector_type(4)));
typedef float  f32x4  __attribute__((ext_vector_type(4)));
typedef _Float16 f16_t;
typedef _Float16 f16x2 __attribute__((ext_vector_type(2)));
typedef _Float16 f16x4 __attribute__((ext_vector_type(4)));
typedef int v4i __attribute__((ext_vector_type(4)));

#define EPSV 1e-5f

#define GLD(dst, ptr, off) \
    asm volatile("global_load_dwordx4 %0, %1, off offset:%c2" \
                 : "=v"(dst) : "v"(ptr), "n"(off) : "memory")
#define WAITV(n) do { \
    asm volatile("s_waitcnt vmcnt(%c0)" :: "n"(n) : "memory"); \
    __builtin_amdgcn_sched_barrier(0); } while (0)

__device__ __forceinline__ bf16x8 as_bf16x8(v4i v) {
    union { v4i i; bf16x8 h; } u; u.i = v; return u.h;
}

// pair-coalesced 16B store: pairs (2k,2k+1) share one chunk; even lane
// stores elems 0-3 (own) + 4-7 (odd partner's) as one aligned v4i.
__device__ __forceinline__ void pair_store16(bf16_t* even_addr, bf16x4 v, int t) {
    union { bf16x4 h; unsigned u[2]; } a; a.h = v;
    const unsigned ox = __shfl_down(a.u[0], 1);
    const unsigned oy = __shfl_down(a.u[1], 1);
    if (!(t & 1)) {
        union { unsigned u[4]; v4i i; } o;
        o.u[0] = a.u[0]; o.u[1] = a.u[1]; o.u[2] = ox; o.u[3] = oy;
        *(v4i*)even_addr = o.i;
    }
}

// ---- workspace offsets (bytes) -------------------------------------------
#define OFF_TEXTP    0u          //  524288  bf16 textP  [16 rb][32 kc][512]
#define OFF_AUDIOP   524288u     // 2097152  bf16 audioP [64 rb][32 kc][512]
#define OFF_W1TOP    2621440u    // 2097152  bf16 topP   [64 rb][32 kc][512]
#define OFF_W1BOT    4718592u    // 2097152  bf16 botP   [64 rb][32 kc][512]
#define OFF_WC1      6815744u    // 6291456  bf16 wc1P [3][64 rb][32 kc][512]
#define OFF_WC2      13107200u   // 6291456  bf16 wc2P (g-scaled)
#define OFF_TP       19398656u   //  524288  f16 tp [256 bt][1024 d]
#define OFF_W2F      19922944u   //    2048  f16 w2 [1024]
#define OFF_APT      20447232u   // 2097152  f16 apT4 [256 hq][1024 ba][4]
#define OFF_XP0      22544384u   //  532480  bf16 xp0 [2][130][1024] row-major
#define OFF_XP1      23076864u   //  532480  bf16 xp1 [2][130][1024] raw relu
#define OFF_Y2       23609344u   //  524288  bf16 y2 [256][1024]
#define OFF_BST1     24133632u   //    4096  f32 bstat1 [512][2]
#define OFF_BST2     24137728u   //    4096  f32 bstat2 [512][2]
#define OFF_SG       26238976u   //   12288  f32 Sg3 [1024][3]
#define OFF_SB       26251264u   //   12288  f32 Sb3 [1024][3]
#define OFF_SGF      26263552u   //    4096  f32 SgF [1024]
#define OFF_SBF      26267648u   //    4096  f32 SbF [1024]

// ---------------------------------------------------------------------------
// prep: [0,1280) act cvt; [1280,3328) w1 transpose-pack; [3328,4352) wc1
// pack; 4352: zero pads + w2->f16.  (verbatim R22)
// ---------------------------------------------------------------------------
__global__ __launch_bounds__(256) void prep_k(
    const float* __restrict__ text, const float* __restrict__ audio,
    const float* __restrict__ w1,
    const float* __restrict__ w1c, const float* __restrict__ w2,
    bf16_t* __restrict__ textP, bf16_t* __restrict__ xp0,
    bf16_t* __restrict__ audioP,
    bf16_t* __restrict__ topP, bf16_t* __restrict__ botP,
    bf16_t* __restrict__ wc1,
    bf16_t* __restrict__ xp1, f16_t* __restrict__ w2f)
{
    __shared__ float tile[32][33];
    const int bid = blockIdx.x;
    const int tid = threadIdx.x;
    if (bid < 1280) {
        const int e = (bid * 256 + tid) * 4;   // 1310720 total; h = 4*tid
        if (e < 262144) {
            float4 v = *(const float4*)&text[e];
            bf16x4 o; o[0] = (bf16_t)v.x; o[1] = (bf16_t)v.y; o[2] = (bf16_t)v.z; o[3] = (bf16_t)v.w;
            const int bt = e >> 10, h = e & 1023;
            const int b = bt >> 7, t = bt & 127;
            *(bf16x4*)&xp0[(size_t)(b * 130 + 1 + t) * 1024 + h] = o;
            const int h0 = h & ~7;             // even-thread h
            const int lane = (bt & 15) | (((h0 >> 3) & 3) << 4);
            bf16_t* ea = &textP[((size_t)((bt >> 4) * 32 + (h0 >> 5))) * 512 + lane * 8];
            pair_store16(ea, o, tid);
        } else {
            const int ea4 = e - 262144;
            float4 v = *(const float4*)&audio[ea4];
            bf16x4 o; o[0] = (bf16_t)v.x; o[1] = (bf16_t)v.y; o[2] = (bf16_t)v.z; o[3] = (bf16_t)v.w;
            const int ba = ea4 >> 10, h = ea4 & 1023;
            const int h0 = h & ~7;
            const int lane = (ba & 15) | (((h0 >> 3) & 3) << 4);
            bf16_t* ea = &audioP[((size_t)((ba >> 4) * 32 + (h0 >> 5))) * 512 + lane * 8];
            pair_store16(ea, o, tid);
        }
    } else if (bid < 3328) {
        const int b2 = bid - 1280;
        const int bx = b2 & 31, by = b2 >> 5;          // bx: d-blk(32), by: h-blk(64)
        const int tx = tid & 31, ty = tid >> 5;
        #pragma unroll
        for (int j = 0; j < 4; ++j)
            tile[ty + j * 8][tx] = w1[(size_t)(by * 32 + ty + j * 8) * 1024 + bx * 32 + tx];
        __syncthreads();
        if (tid < 128) {
            const int rbl = tid >> 6, lane = tid & 63;
            const int dl = rbl * 16 + (lane & 15);
            const int lkp = lane >> 4;
            bf16x8 v8;
            #pragma unroll
            for (int e2 = 0; e2 < 8; ++e2) v8[e2] = (bf16_t)tile[lkp * 8 + e2][dl];
            const int d = bx * 32 + dl;
            bf16_t* out = (by < 32) ? topP : botP;
            *(bf16x8*)&out[((size_t)((d >> 4) * 32 + (by & 31))) * 512 + lane * 8] = v8;
        }
    } else if (bid < 4352) {
        const int o = bid - 3328;                      // wc1 chan
        const int i0 = tid * 4;
        const float* src = w1c + (size_t)o * 3072 + tid * 12;
        float4 v0 = *(const float4*)&src[0];
        float4 v1 = *(const float4*)&src[4];
        float4 v2 = *(const float4*)&src[8];
        const float f[12] = {v0.x, v0.y, v0.z, v0.w, v1.x, v1.y, v1.z, v1.w, v2.x, v2.y, v2.z, v2.w};
        const int ip = i0 & ~7;                        // even-thread i0
        const int lane = (o & 15) | (((ip >> 3) & 3) << 4);
        #pragma unroll
        for (int r = 0; r < 3; ++r) {
            bf16x4 o4;
            #pragma unroll
            for (int j = 0; j < 4; ++j) o4[j] = (bf16_t)f[j * 3 + r];
            bf16_t* ea = &wc1[((size_t)(r * 2048 + (o >> 4) * 32 + (ip >> 5))) * 512 + lane * 8];
            pair_store16(ea, o4, tid);
        }
    } else {
        const int rowmap[4] = {0, 129, 130, 259};
        const int f = tid * 16;
        const int r = f >> 10, w = f & 1023;
        bf16x8 z8 = (bf16x8)(bf16_t)0.0f;
        bf16_t* p0 = xp0 + (size_t)rowmap[r] * 1024 + w;
        bf16_t* p1 = xp1 + (size_t)rowmap[r] * 1024 + w;
        *(bf16x8*)p0 = z8; *(bf16x8*)(p0 + 8) = z8;
        *(bf16x8*)p1 = z8; *(bf16x8*)(p1 + 8) = z8;
        float4 wv = *(const float4*)&w2[tid * 4];
        f16x4 wo; wo[0] = (f16_t)wv.x; wo[1] = (f16_t)wv.y; wo[2] = (f16_t)wv.z; wo[3] = (f16_t)wv.w;
        *(f16x4*)&w2f[tid * 4] = wo;
    }
}

// ---------------------------------------------------------------------------
// helpers
// ---------------------------------------------------------------------------
__device__ __forceinline__ float wave_red_add(float v) {
    #pragma unroll
    for (int off = 32; off > 0; off >>= 1) v += __shfl_xor(v, off);
    return v;
}

// Conv MFMA body (R22): weights fragment-packed (contiguous 1KB loads
// issued before LDS staging); activations staged in padded LDS [34][264].
__device__ __forceinline__ void conv_body(
    const bf16_t* __restrict__ WcP, const bf16_t* __restrict__ xp,
    int by, int b, int tbase, int w, int l, bf16_t* Bs, int tid,
    f32x4& acc0, f32x4& acc1)
{
    const int lm = l & 15, lk = (l >> 4) * 8;
    const bf16_t* xrow = xp + (size_t)(b * 130 + tbase) * 1024;
    #pragma unroll 1
    for (int c = 0; c < 4; ++c) {
        __syncthreads();
        const int kc = c * 8 + w;
        const bf16_t* a0 = WcP + ((size_t)(by * 32 + kc)) * 512 + l * 8;
        v4i A0, A1, A2;
        GLD(A0, a0, 0);
        GLD(A1, a0 + 1048576, 0);
        GLD(A2, a0 + 2097152, 0);
        for (int idx = tid; idx < 1088; idx += 512) {
            const int row = idx >> 5, col = (idx & 31) * 8;
            *(v4i*)&Bs[row * 264 + col] =
                *(const v4i*)&xrow[(size_t)row * 1024 + c * 256 + col];
        }
        __syncthreads();
        const int cb = w * 32 + lk;
        bf16x8 b00 = *(const bf16x8*)&Bs[(lm + 0) * 264 + cb];
        bf16x8 b10 = *(const bf16x8*)&Bs[(lm + 16) * 264 + cb];
        bf16x8 b01 = *(const bf16x8*)&Bs[(lm + 1) * 264 + cb];
        bf16x8 b11 = *(const bf16x8*)&Bs[(lm + 17) * 264 + cb];
        bf16x8 b02 = *(const bf16x8*)&Bs[(lm + 2) * 264 + cb];
        bf16x8 b12 = *(const bf16x8*)&Bs[(lm + 18) * 264 + cb];
        WAITV(2);
        acc0 = __builtin_amdgcn_mfma_f32_16x16x32_bf16(as_bf16x8(A0), b00, acc0, 0, 0, 0);
        acc1 = __builtin_amdgcn_mfma_f32_16x16x32_bf16(as_bf16x8(A0), b10, acc1, 0, 0, 0);
        WAITV(1);
        acc0 = __builtin_amdgcn_mfma_f32_16x16x32_bf16(as_bf16x8(A1), b01, acc0, 0, 0, 0);
        acc1 = __builtin_amdgcn_mfma_f32_16x16x32_bf16(as_bf16x8(A1), b11, acc1, 0, 0, 0);
        WAITV(0);
        acc0 = __builtin_amdgcn_mfma_f32_16x16x32_bf16(as_bf16x8(A2), b02, acc0, 0, 0, 0);
        acc1 = __builtin_amdgcn_mfma_f32_16x16x32_bf16(as_bf16x8(A2), b12, acc1, 0, 0, 0);
    }
    __syncthreads();
}

// ---------------------------------------------------------------------------
// P2: [0,512) conv1; [512,768) tp gemm; [768,1792) ap gemm;
//     [1792,2304) wc2 fragment-pack (2 chans/block) + Sg/Sb/SgF/SbF.
// (verbatim R22)
// ---------------------------------------------------------------------------
__global__ __launch_bounds__(512) void p2_k(
    const bf16_t* __restrict__ wc1, const bf16_t* __restrict__ xp0,
    const float* __restrict__ d_b1, bf16_t* __restrict__ xp1,
    float* __restrict__ bstat1,
    const bf16_t* __restrict__ textP, const bf16_t* __restrict__ topP,
    const float* __restrict__ a_b1, f16_t* __restrict__ tp,
    const bf16_t* __restrict__ audioP, const bf16_t* __restrict__ botP,
    f16_t* __restrict__ apT4,
    const float* __restrict__ w2c, const float* __restrict__ g1,
    const float* __restrict__ b1g, bf16_t* __restrict__ wc2,
    float* __restrict__ Sg3, float* __restrict__ Sb3,
    float* __restrict__ SgF, float* __restrict__ SbF)
{
    __shared__ float smem[8448];
    __shared__ float sred[8], sredq[8];
    const int bid = blockIdx.x;
    const int tid = threadIdx.x;
    const int w = tid >> 6, l = tid & 63;
    const int lm = l & 15, lh = l >> 4;
    if (bid < 512) {
        const int bx = bid >> 6, by = bid & 63;
        const int bt0 = bx * 32, m0 = by * 16;
        const int b = bt0 >> 7, tbase = bt0 & 127;
        f32x4 acc0 = (f32x4)(0.0f), acc1 = (f32x4)(0.0f);
        conv_body(wc1, xp0, by, b, tbase, w, l, (bf16_t*)smem, tid, acc0, acc1);
        float* sl = smem + w * 528;
        #pragma unroll
        for (int r = 0; r < 4; ++r) {
            sl[(lh * 4 + r) * 33 + lm] = acc0[r];
            sl[(lh * 4 + r) * 33 + 16 + lm] = acc1[r];
        }
        __syncthreads();
        const int mm = tid >> 5, nn = tid & 31;  // chan-local, bt-local
        float v = 0.f;
        #pragma unroll
        for (int ww = 0; ww < 8; ++ww) v += smem[ww * 528 + mm * 33 + nn];
        v = fmaxf(v + d_b1[m0 + mm], 0.f);
        float s = wave_red_add(v), q = wave_red_add(v * v);
        if (l == 0) { sred[w] = s; sredq[w] = q; }
        xp1[(size_t)(b * 130 + 1 + tbase + nn) * 1024 + m0 + mm] = (bf16_t)v;
        __syncthreads();
        if (tid == 0) {
            float ts = 0.f, tq = 0.f;
            #pragma unroll
            for (int ww = 0; ww < 8; ++ww) { ts += sred[ww]; tq += sredq[ww]; }
            bstat1[bid * 2] = ts; bstat1[bid * 2 + 1] = tq;
        }
    } else if (bid < 1792) {
        // gemm 32x32 tile, 8-way K-split; fragment-packed operands.
        const bf16_t *At, *Bm;
        int d0, r0, is_tp;
        if (bid < 768) {
            const int unit = bid - 512;          // 256 units: 8 bt x 32 d
            d0 = (unit & 31) * 32; r0 = (unit >> 5) * 32;
            At = topP; Bm = textP; is_tp = 1;
        } else {
            const int unit = bid - 768;          // 1024 units: 32 a x 32 d
            d0 = (unit & 31) * 32; r0 = (unit >> 5) * 32;
            At = botP; Bm = audioP; is_tp = 0;
        }
        const int rb0 = d0 >> 4, rbB = r0 >> 4;
        const bf16_t* Ap0 = At + ((size_t)(rb0 * 32 + w * 4)) * 512 + l * 8;
        const bf16_t* Ap1 = Ap0 + 16384;
        const bf16_t* Bp0 = Bm + ((size_t)(rbB * 32 + w * 4)) * 512 + l * 8;
        const bf16_t* Bp1 = Bp0 + 16384;
        v4i qa0[4], qa1[4], qb0[4], qb1[4];
        GLD(qa0[0], Ap0,    0); GLD(qa1[0], Ap1,    0); GLD(qb0[0], Bp0,    0); GLD(qb1[0], Bp1,    0);
        GLD(qa0[1], Ap0, 1024); GLD(qa1[1], Ap1, 1024); GLD(qb0[1], Bp0, 1024); GLD(qb1[1], Bp1, 1024);
        GLD(qa0[2], Ap0, 2048); GLD(qa1[2], Ap1, 2048); GLD(qb0[2], Bp0, 2048); GLD(qb1[2], Bp1, 2048);
        GLD(qa0[3], Ap0, 3072); GLD(qa1[3], Ap1, 3072); GLD(qb0[3], Bp0, 3072); GLD(qb1[3], Bp1, 3072);
        f32x4 acc[2][2];
        #pragma unroll
        for (int mt = 0; mt < 2; ++mt)
            #pragma unroll
            for (int nt = 0; nt < 2; ++nt) acc[mt][nt] = (f32x4)(0.0f);
#define GMF(cc, n) \
        WAITV(n); \
        acc[0][0] = __builtin_amdgcn_mfma_f32_16x16x32_bf16(as_bf16x8(qa0[cc]), as_bf16x8(qb0[cc]), acc[0][0], 0, 0, 0); \
        acc[0][1] = __builtin_amdgcn_mfma_f32_16x16x32_bf16(as_bf16x8(qa0[cc]), as_bf16x8(qb1[cc]), acc[0][1], 0, 0, 0); \
        acc[1][0] = __builtin_amdgcn_mfma_f32_16x16x32_bf16(as_bf16x8(qa1[cc]), as_bf16x8(qb0[cc]), acc[1][0], 0, 0, 0); \
        acc[1][1] = __builtin_amdgcn_mfma_f32_16x16x32_bf16(as_bf16x8(qa1[cc]), as_bf16x8(qb1[cc]), acc[1][1], 0, 0, 0)
        GMF(0, 12); GMF(1, 8); GMF(2, 4); GMF(3, 0);
#undef GMF
        float* sl = smem + w * 1056;
        #pragma unroll
        for (int mt = 0; mt < 2; ++mt)
            #pragma unroll
            for (int nt = 0; nt < 2; ++nt)
                #pragma unroll
                for (int r = 0; r < 4; ++r)
                    sl[(mt * 16 + lh * 4 + r) * 33 + nt * 16 + lm] = acc[mt][nt][r];
        __syncthreads();
        const int m = tid >> 4, n2 = (tid & 15) * 2;     // d-local, row-local pair
        float v0 = 0.f, v1 = 0.f;
        #pragma unroll
        for (int ww = 0; ww < 8; ++ww) {
            v0 += smem[ww * 1056 + m * 33 + n2];
            v1 += smem[ww * 1056 + m * 33 + n2 + 1];
        }
        if (is_tp) {
            const float bb = a_b1[d0 + m];
            tp[(size_t)(r0 + n2) * 1024 + d0 + m] = (f16_t)(v0 + bb);
            tp[(size_t)(r0 + n2 + 1) * 1024 + d0 + m] = (f16_t)(v1 + bb);
        } else {
            const int h = d0 + m, hq = h >> 2, hr = h & 3;
            const int a0 = r0 + n2;
            const int bbk = a0 >> 9, al = a0 & 511;
            apT4[((size_t)hq * 1024 + bbk * 512 + al) * 4 + hr] = (f16_t)v0;
            apT4[((size_t)hq * 1024 + bbk * 512 + al + 1) * 4 + hr] = (f16_t)v1;
        }
    } else {
        // ---- wc2 fragment-pack + Sg/Sb/SgF/SbF (2 chans/block) ----------
        const int half = tid >> 8, t = tid & 255;
        const int o = (bid - 1792) * 2 + half;
        const int i0 = t * 4;
        const float* src = w2c + (size_t)o * 3072 + t * 12;
        float4 v0 = *(const float4*)&src[0];
        float4 v1 = *(const float4*)&src[4];
        float4 v2 = *(const float4*)&src[8];
        const float f[12] = {v0.x, v0.y, v0.z, v0.w, v1.x, v1.y, v1.z, v1.w, v2.x, v2.y, v2.z, v2.w};
        float4 gv = *(const float4*)&g1[i0];
        float4 bv = *(const float4*)&b1g[i0];
        const float g4[4] = {gv.x, gv.y, gv.z, gv.w};
        const float bb4[4] = {bv.x, bv.y, bv.z, bv.w};
        const int ip = i0 & ~7;
        const int lane = (o & 15) | (((ip >> 3) & 3) << 4);
        float sgr[3] = {0.f, 0.f, 0.f}, sbr[3] = {0.f, 0.f, 0.f};
        #pragma unroll
        for (int r = 0; r < 3; ++r) {
            bf16x4 o4;
            #pragma unroll
            for (int j = 0; j < 4; ++j) {
                const float wv = f[j * 3 + r];
                const float ws = wv * g4[j];
                sgr[r] += ws;
                sbr[r] += wv * bb4[j];
                o4[j] = (bf16_t)ws;
            }
            bf16_t* ea = &wc2[((size_t)(r * 2048 + (o >> 4) * 32 + (ip >> 5))) * 512 + lane * 8];
            pair_store16(ea, o4, t);
        }
        #pragma unroll
        for (int off = 32; off > 0; off >>= 1) {
            #pragma unroll
            for (int r = 0; r < 3; ++r) {
                sgr[r] += __shfl_xor(sgr[r], off);
                sbr[r] += __shfl_xor(sbr[r], off);
            }
        }
        float* red = smem + half * 32;
        const int wid = t >> 6, lane2 = t & 63;
        if (lane2 == 0) {
            #pragma unroll
            for (int r = 0; r < 3; ++r) {
                red[wid * 6 + r] = sgr[r];
                red[wid * 6 + 3 + r] = sbr[r];
            }
        }
        __syncthreads();
        if (t < 6) {
            const float v = red[t] + red[6 + t] + red[12 + t] + red[18 + t];
            if (t < 3) Sg3[o * 3 + t] = v;
            else       Sb3[o * 3 + t - 3] = v;
            red[24 + t] = v;
        }
        __syncthreads();
        if (t == 0)      SgF[o] = red[24] + red[25] + red[26];
        else if (t == 1) SbF[o] = red[27] + red[28] + red[29];
    }
}

// reduce 256 (s,q) pairs for batch b from bstat (block-level, 512 threads).
__device__ __forceinline__ void reduce_bstat(
    const float* __restrict__ bstat, int b, int tid,
    float* sr, float* sq, float& mu, float& rsig)
{
    const int lane = tid & 63, wid = tid >> 6;
    float s = 0.f, q = 0.f;
    if (tid < 256) {
        float2 v = ((const float2*)bstat)[b * 256 + tid];
        s = v.x; q = v.y;
    }
    #pragma unroll
    for (int off = 32; off > 0; off >>= 1) {
        s += __shfl_xor(s, off);
        q += __shfl_xor(q, off);
    }
    if (lane == 0) { sr[wid] = s; sq[wid] = q; }
    __syncthreads();
    float ts = 0.f, tq = 0.f;
    #pragma unroll
    for (int i = 0; i < 8; ++i) { ts += sr[i]; tq += sq[i]; }
    const float cnt = 131072.f;
    mu = ts / cnt;
    const float var = tq / cnt - mu * mu;
    rsig = rsqrtf(var + EPSV);
}

// ---------------------------------------------------------------------------
// P3: [0,512) conv2 tiles (GN1 folded); [512,576) logits+softmax blocks
//     (4 bt-rows x 512 a, FULL h range, softmax inline -> out).
// ---------------------------------------------------------------------------
__device__ __forceinline__ float dot2_acc(f16x2 x, f16x2 w, float acc) {
#if __has_builtin(__builtin_amdgcn_fdot2)
    return __builtin_amdgcn_fdot2(x, w, acc, false);
#else
    return acc + (float)x[0] * (float)w[0] + (float)x[1] * (float)w[1];
#endif
}

__global__ __launch_bounds__(512) void p3_k(
    const bf16_t* __restrict__ wc2, const bf16_t* __restrict__ xp1,
    const float* __restrict__ d_b2, bf16_t* __restrict__ y2,
    float* __restrict__ bstat2, const float* __restrict__ bstat1,
    const float* __restrict__ SgF, const float* __restrict__ SbF,
    const float* __restrict__ Sg3, const float* __restrict__ Sb3,
    const f16_t* __restrict__ tp, const f16_t* __restrict__ apT4,
    const f16_t* __restrict__ w2f, const float* __restrict__ ab2,
    float* __restrict__ out)
{
    __shared__ float smem[4608];                 // conv: Bs bf16[34][264] then [8][16][33]
    __shared__ float sred[8], sredq[8], sr[8], sq[8];
    __shared__ float redm[32], redsum[32];
    const int bid = blockIdx.x;
    const int tid = threadIdx.x;
    if (bid < 512) {
        const int w = tid >> 6, l = tid & 63;
        const int lm = l & 15, lh = l >> 4;
        const int bx = bid >> 6, by = bid & 63;
        const int bt0 = bx * 32, m0 = by * 16;
        const int b = bt0 >> 7, tbase = bt0 & 127;
        f32x4 acc0 = (f32x4)(0.0f), acc1 = (f32x4)(0.0f);
        conv_body(wc2, xp1, by, b, tbase, w, l, (bf16_t*)smem, tid, acc0, acc1);
        float* sl = smem + w * 528;
        #pragma unroll
        for (int r = 0; r < 4; ++r) {
            sl[(lh * 4 + r) * 33 + lm] = acc0[r];
            sl[(lh * 4 + r) * 33 + 16 + lm] = acc1[r];
        }
        __syncthreads();
        const int mm = tid >> 5, nn = tid & 31;
        float vraw = 0.f;
        #pragma unroll
        for (int ww = 0; ww < 8; ++ww) vraw += smem[ww * 528 + mm * 33 + nn];
        float mu, rsig;
        reduce_bstat(bstat1, b, tid, sr, sq, mu, rsig);   // has its own barrier
        const int o = m0 + mm, tloc = tbase + nn;
        float sg = SgF[o], sb = SbF[o];
        if (tloc == 0)   { sg -= Sg3[o * 3];     sb -= Sb3[o * 3]; }
        if (tloc == 127) { sg -= Sg3[o * 3 + 2]; sb -= Sb3[o * 3 + 2]; }
        float v = fmaxf(rsig * vraw + sb - mu * rsig * sg + d_b2[o], 0.f);
        float s = wave_red_add(v), q = wave_red_add(v * v);
        if ((tid & 63) == 0) { sred[tid >> 6] = s; sredq[tid >> 6] = q; }
        y2[(size_t)(b * 128 + tloc) * 1024 + o] = (bf16_t)v;
        __syncthreads();
        if (tid == 0) {
            float ts = 0.f, tq = 0.f;
            #pragma unroll
            for (int ww = 0; ww < 8; ++ww) { ts += sred[ww]; tq += sredq[ww]; }
            bstat2[bid * 2] = ts; bstat2[bid * 2 + 1] = tq;
        }
    } else {
        // ---- logits + inline softmax: 64 blocks, 4 bt rows, full h -------
        const int btp = bid - 512;                      // 0..63
        const int bt0 = btp * 4;
        const int b = bt0 >> 7, tbase = bt0 & 127;
        const int a = tid;                              // 0..511
        const int lane = tid & 63, wid = tid >> 6;
        const f16_t* tpr = tp + (size_t)bt0 * 1024;     // wave-uniform
        const f16_t* apc = apT4 + ((size_t)(b * 512 + a)) * 4;
        float acc[4] = {0.f, 0.f, 0.f, 0.f};
        const f16x2 zero = (f16x2)(f16_t)0.0f;
#define L_A0(i) (*(const f16x4*)(apc + (size_t)(2 * (i)) * 4096))
#define L_A1(i) (*(const f16x4*)(apc + (size_t)(2 * (i) + 1) * 4096))
        constexpr int PF = 4;
        f16x4 pa[PF], pb[PF];
        #pragma unroll
        for (int i = 0; i < PF; ++i) { pa[i] = L_A0(i); pb[i] = L_A1(i); }
        #pragma unroll 2
        for (int i = 0; i < 128; ++i) {                 // hq pair per iter
            const int sl = i % PF;
            const int hq = 2 * i;
            f16x4 a0 = pa[sl], a1 = pb[sl];
            f16x4 w0 = *(const f16x4*)&w2f[hq * 4];
            f16x4 w1 = *(const f16x4*)&w2f[hq * 4 + 4];
            #pragma unroll
            for (int r = 0; r < 4; ++r) {
                f16x4 t0 = *(const f16x4*)&tpr[r * 1024 + hq * 4];
                f16x4 t1 = *(const f16x4*)&tpr[r * 1024 + hq * 4 + 4];
                f16x2 p;
                p = __builtin_elementwise_max((f16x2){t0[0] + a0[0], t0[1] + a0[1]}, zero);
                acc[r] = dot2_acc(p, (f16x2){w0[0], w0[1]}, acc[r]);
                p = __builtin_elementwise_max((f16x2){t0[2] + a0[2], t0[3] + a0[3]}, zero);
                acc[r] = dot2_acc(p, (f16x2){w0[2], w0[3]}, acc[r]);
                p = __builtin_elementwise_max((f16x2){t1[0] + a1[0], t1[1] + a1[1]}, zero);
                acc[r] = dot2_acc(p, (f16x2){w1[0], w1[1]}, acc[r]);
                p = __builtin_elementwise_max((f16x2){t1[2] + a1[2], t1[3] + a1[3]}, zero);
                acc[r] = dot2_acc(p, (f16x2){w1[2], w1[3]}, acc[r]);
            }
            const int nx = i + PF;
            if (nx < 128) { pa[sl] = L_A0(nx); pb[sl] = L_A1(nx); }
        }
#undef L_A0
#undef L_A1
        const float b2v = ab2[0];
        float vv[4], mx[4];
        #pragma unroll
        for (int r = 0; r < 4; ++r) {
            vv[r] = acc[r] + b2v - 0.1f * fabsf((float)a - 4.0f * (float)(tbase + r));
            mx[r] = vv[r];
        }
        #pragma unroll
        for (int off = 32; off > 0; off >>= 1)
            #pragma unroll
            for (int r = 0; r < 4; ++r) mx[r] = fmaxf(mx[r], __shfl_xor(mx[r], off));
        if (lane == 0) {
            #pragma unroll
            for (int r = 0; r < 4; ++r) redm[wid * 4 + r] = mx[r];
        }
        __syncthreads();
        float M[4], ee[4], ss[4];
        #pragma unroll
        for (int r = 0; r < 4; ++r) {
            M[r] = redm[r];
            #pragma unroll
            for (int i = 1; i < 8; ++i) M[r] = fmaxf(M[r], redm[i * 4 + r]);
            ee[r] = expf(vv[r] - M[r]);
            ss[r] = ee[r];
        }
        #pragma unroll
        for (int off = 32; off > 0; off >>= 1)
            #pragma unroll
            for (int r = 0; r < 4; ++r) ss[r] += __shfl_xor(ss[r], off);
        if (lane == 0) {
            #pragma unroll
            for (int r = 0; r < 4; ++r) redsum[wid * 4 + r] = ss[r];
        }
        __syncthreads();
        #pragma unroll
        for (int r = 0; r < 4; ++r) {
            float S = redsum[r];
            #pragma unroll
            for (int i = 1; i < 8; ++i) S += redsum[i * 4 + r];
            out[(size_t)(bt0 + r) * 512 + a] = ee[r] * (1.0f / S);
        }
    }
}

// ---------------------------------------------------------------------------
// combine: 32 blocks — conv3 + GN2 (reduced from bstat2) + softplus only.
// ---------------------------------------------------------------------------
__global__ __launch_bounds__(512) void combine_k(
    const bf16_t* __restrict__ y2, const float* __restrict__ bstat2,
    const float* __restrict__ g, const float* __restrict__ bet,
    const float* __restrict__ w3, const float* __restrict__ b3,
    float* __restrict__ out)
{
    __shared__ float redm[8], redsum[8];
    const int cb = blockIdx.x;             // 0..31, bt [cb*8, cb*8+8)
    const int tid = threadIdx.x;
    const int b = (cb * 8) >> 7;
    float mu, rsig;
    reduce_bstat(bstat2, b, tid, redm, redsum, mu, rsig);
    const int lane = tid & 63, w = tid >> 6;
    const int bt = cb * 8 + w;
    const bf16_t* row = y2 + (size_t)bt * 1024 + lane * 16;
    float s1 = 0.f, s2 = 0.f, s3 = 0.f;
    #pragma unroll
    for (int c = 0; c < 2; ++c) {
        bf16x8 yv = *(const bf16x8*)(row + c * 8);
        #pragma unroll
        for (int j = 0; j < 8; ++j) {
            const int i = lane * 16 + c * 8 + j;
            const float gw = g[i] * w3[i];
            s1 += gw * (float)yv[j];
            s2 += gw;
            s3 += bet[i] * w3[i];
        }
    }
    #pragma unroll
    for (int off = 32; off > 0; off >>= 1) {
        s1 += __shfl_xor(s1, off);
        s2 += __shfl_xor(s2, off);
        s3 += __shfl_xor(s3, off);
    }
    if (lane == 0) {
        const float t = rsig * (s1 - mu * s2) + s3 + b3[0];
        out[131072 + bt] = fmaxf(t, 0.f) + log1pf(expf(-fabsf(t)));
    }
}

extern "C" void kernel_launch(void* const* d_in, const int* in_sizes, int n_in,
                              void* d_out, int out_size, void* d_ws, size_t ws_size,
                              hipStream_t stream) {
    const float* text   = (const float*)d_in[0];
    const float* audio  = (const float*)d_in[1];
    const float* a_w1   = (const float*)d_in[2];
    const float* a_b1   = (const float*)d_in[3];
    const float* a_w2   = (const float*)d_in[4];
    const float* a_b2   = (const float*)d_in[5];
    const float* d_w1   = (const float*)d_in[6];
    const float* d_b1   = (const float*)d_in[7];
    const float* gn1_g  = (const float*)d_in[8];
    const float* gn1_b  = (const float*)d_in[9];
    const float* d_w2   = (const float*)d_in[10];
    const float* d_b2   = (const float*)d_in[11];
    const float* gn2_g  = (const float*)d_in[12];
    const float* gn2_b  = (const float*)d_in[13];
    const float* d_w3   = (const float*)d_in[14];
    const float* d_b3   = (const float*)d_in[15];

    char* ws = (char*)d_ws;
    float* outf = (float*)d_out;

    bf16_t* textP    = (bf16_t*)(ws + OFF_TEXTP);
    bf16_t* audioP   = (bf16_t*)(ws + OFF_AUDIOP);
    bf16_t* topP     = (bf16_t*)(ws + OFF_W1TOP);
    bf16_t* botP     = (bf16_t*)(ws + OFF_W1BOT);
    bf16_t* wc1      = (bf16_t*)(ws + OFF_WC1);
    bf16_t* wc2      = (bf16_t*)(ws + OFF_WC2);
    f16_t*  tp       = (f16_t*) (ws + OFF_TP);
    f16_t*  w2f      = (f16_t*) (ws + OFF_W2F);
    f16_t*  apT4     = (f16_t*) (ws + OFF_APT);
    bf16_t* xp0      = (bf16_t*)(ws + OFF_XP0);
    bf16_t* xp1      = (bf16_t*)(ws + OFF_XP1);
    bf16_t* y2       = (bf16_t*)(ws + OFF_Y2);
    float*  bstat1   = (float*) (ws + OFF_BST1);
    float*  bstat2   = (float*) (ws + OFF_BST2);
    float*  Sg3      = (float*) (ws + OFF_SG);
    float*  Sb3      = (float*) (ws + OFF_SB);
    float*  SgFp     = (float*) (ws + OFF_SGF);
    float*  SbFp     = (float*) (ws + OFF_SBF);

    // 1: prep (act pack, w1 pack, wc1 pack, pads, w2f)
    prep_k<<<dim3(4353), 256, 0, stream>>>(text, audio, a_w1, d_w1, a_w2,
                                           textP, xp0, audioP, topP, botP,
                                           wc1, xp1, w2f);
    // 2: conv1 (512) ∥ tp gemm (256) ∥ ap gemm (1024) ∥ wc2-pack (512)
    p2_k<<<dim3(2304), 512, 0, stream>>>(wc1, xp0, d_b1, xp1, bstat1,
                                         textP, topP, a_b1, tp,
                                         audioP, botP, apT4,
                                         d_w2, gn1_g, gn1_b, wc2,
                                         Sg3, Sb3, SgFp, SbFp);
    // 3: conv2 (512, GN1 folded) ∥ logits+softmax (64) — 576 x 512 thr
    p3_k<<<dim3(576), 512, 0, stream>>>(wc2, xp1, d_b2, y2, bstat2, bstat1,
                                        SgFp, SbFp, Sg3, Sb3, tp, apT4, w2f,
                                        a_b2, outf);
    // 4: conv3 + GN2(reduced) + softplus -> durations (32 blocks)
    combine_k<<<dim3(32), 512, 0, stream>>>(y2, bstat2,
                                            gn2_g, gn2_b, d_w3, d_b3, outf);
}

// Round 14
// 150.874 us; speedup vs baseline: 3.3472x; 3.3472x over previous
//
#include <hip/hip_runtime.h>
#include <hip/hip_bf16.h>

// ---------------------------------------------------------------------------
// MonotonicAlignmentSearch R26: resubmit of R25 (= exact R22 config, best
// measured 150.6us in Round 10). R25's bench failed on container acquisition
// ("MI355X container failed twice"), not on the kernel. No source changes.
// Structure: prep (pack) -> p2 (conv1 || tp/ap gemm || wc2-pack) ->
// p3 (conv2 GN1-folded || logits partials) -> combine (softmax || conv3+GN2).
// B=2, TT=128, TA=512, H=1024.
// ---------------------------------------------------------------------------

typedef __bf16 bf16_t;
typedef __bf16 bf16x8 __attribute__((ext_vector_type(8)));
typedef __bf16 bf16x4 __attribute__((ext_vector_type(4)));
typedef float  f32x4  __attribute__((ext_vector_type(4)));
typedef _Float16 f16_t;
typedef _Float16 f16x2 __attribute__((ext_vector_type(2)));
typedef _Float16 f16x4 __attribute__((ext_vector_type(4)));
typedef int v4i __attribute__((ext_vector_type(4)));

#define EPSV 1e-5f

#define GLD(dst, ptr, off) \
    asm volatile("global_load_dwordx4 %0, %1, off offset:%c2" \
                 : "=v"(dst) : "v"(ptr), "n"(off) : "memory")
#define WAITV(n) do { \
    asm volatile("s_waitcnt vmcnt(%c0)" :: "n"(n) : "memory"); \
    __builtin_amdgcn_sched_barrier(0); } while (0)

__device__ __forceinline__ bf16x8 as_bf16x8(v4i v) {
    union { v4i i; bf16x8 h; } u; u.i = v; return u.h;
}

// pair-coalesced 16B store: pairs (2k,2k+1) share one chunk; even lane
// stores elems 0-3 (own) + 4-7 (odd partner's) as one aligned v4i.
__device__ __forceinline__ void pair_store16(bf16_t* even_addr, bf16x4 v, int t) {
    union { bf16x4 h; unsigned u[2]; } a; a.h = v;
    const unsigned ox = __shfl_down(a.u[0], 1);
    const unsigned oy = __shfl_down(a.u[1], 1);
    if (!(t & 1)) {
        union { unsigned u[4]; v4i i; } o;
        o.u[0] = a.u[0]; o.u[1] = a.u[1]; o.u[2] = ox; o.u[3] = oy;
        *(v4i*)even_addr = o.i;
    }
}

// ---- workspace offsets (bytes) -------------------------------------------
#define OFF_TEXTP    0u          //  524288  bf16 textP  [16 rb][32 kc][512]
#define OFF_AUDIOP   524288u     // 2097152  bf16 audioP [64 rb][32 kc][512]
#define OFF_W1TOP    2621440u    // 2097152  bf16 topP   [64 rb][32 kc][512]
#define OFF_W1BOT    4718592u    // 2097152  bf16 botP   [64 rb][32 kc][512]
#define OFF_WC1      6815744u    // 6291456  bf16 wc1P [3][64 rb][32 kc][512]
#define OFF_WC2      13107200u   // 6291456  bf16 wc2P (g-scaled)
#define OFF_TP       19398656u   //  524288  f16 tp [256 bt][1024 d]
#define OFF_W2F      19922944u   //    2048  f16 w2 [1024]
#define OFF_APT      20447232u   // 2097152  f16 apT4 [256 hq][1024 ba][4]
#define OFF_XP0      22544384u   //  532480  bf16 xp0 [2][130][1024] row-major
#define OFF_XP1      23076864u   //  532480  bf16 xp1 [2][130][1024] raw relu
#define OFF_Y2       23609344u   //  524288  bf16 y2 [256][1024]
#define OFF_BST1     24133632u   //    4096  f32 bstat1 [512][2]
#define OFF_BST2     24137728u   //    4096  f32 bstat2 [512][2]
#define OFF_LP       24141824u   // 2097152  f32 lp [4][256][512]
#define OFF_SG       26238976u   //   12288  f32 Sg3 [1024][3]
#define OFF_SB       26251264u   //   12288  f32 Sb3 [1024][3]
#define OFF_SGF      26263552u   //    4096  f32 SgF [1024]
#define OFF_SBF      26267648u   //    4096  f32 SbF [1024]

// ---------------------------------------------------------------------------
// prep: [0,1280) act cvt; [1280,3328) w1 transpose-pack; [3328,4352) wc1
// pack; 4352: zero pads + w2->f16.
// ---------------------------------------------------------------------------
__global__ __launch_bounds__(256) void prep_k(
    const float* __restrict__ text, const float* __restrict__ audio,
    const float* __restrict__ w1,
    const float* __restrict__ w1c, const float* __restrict__ w2,
    bf16_t* __restrict__ textP, bf16_t* __restrict__ xp0,
    bf16_t* __restrict__ audioP,
    bf16_t* __restrict__ topP, bf16_t* __restrict__ botP,
    bf16_t* __restrict__ wc1,
    bf16_t* __restrict__ xp1, f16_t* __restrict__ w2f)
{
    __shared__ float tile[32][33];
    const int bid = blockIdx.x;
    const int tid = threadIdx.x;
    if (bid < 1280) {
        const int e = (bid * 256 + tid) * 4;   // 1310720 total; h = 4*tid
        if (e < 262144) {
            float4 v = *(const float4*)&text[e];
            bf16x4 o; o[0] = (bf16_t)v.x; o[1] = (bf16_t)v.y; o[2] = (bf16_t)v.z; o[3] = (bf16_t)v.w;
            const int bt = e >> 10, h = e & 1023;
            const int b = bt >> 7, t = bt & 127;
            *(bf16x4*)&xp0[(size_t)(b * 130 + 1 + t) * 1024 + h] = o;
            const int h0 = h & ~7;             // even-thread h
            const int lane = (bt & 15) | (((h0 >> 3) & 3) << 4);
            bf16_t* ea = &textP[((size_t)((bt >> 4) * 32 + (h0 >> 5))) * 512 + lane * 8];
            pair_store16(ea, o, tid);
        } else {
            const int ea4 = e - 262144;
            float4 v = *(const float4*)&audio[ea4];
            bf16x4 o; o[0] = (bf16_t)v.x; o[1] = (bf16_t)v.y; o[2] = (bf16_t)v.z; o[3] = (bf16_t)v.w;
            const int ba = ea4 >> 10, h = ea4 & 1023;
            const int h0 = h & ~7;
            const int lane = (ba & 15) | (((h0 >> 3) & 3) << 4);
            bf16_t* ea = &audioP[((size_t)((ba >> 4) * 32 + (h0 >> 5))) * 512 + lane * 8];
            pair_store16(ea, o, tid);
        }
    } else if (bid < 3328) {
        const int b2 = bid - 1280;
        const int bx = b2 & 31, by = b2 >> 5;          // bx: d-blk(32), by: h-blk(64)
        const int tx = tid & 31, ty = tid >> 5;
        #pragma unroll
        for (int j = 0; j < 4; ++j)
            tile[ty + j * 8][tx] = w1[(size_t)(by * 32 + ty + j * 8) * 1024 + bx * 32 + tx];
        __syncthreads();
        if (tid < 128) {
            const int rbl = tid >> 6, lane = tid & 63;
            const int dl = rbl * 16 + (lane & 15);
            const int lkp = lane >> 4;
            bf16x8 v8;
            #pragma unroll
            for (int e2 = 0; e2 < 8; ++e2) v8[e2] = (bf16_t)tile[lkp * 8 + e2][dl];
            const int d = bx * 32 + dl;
            bf16_t* out = (by < 32) ? topP : botP;
            *(bf16x8*)&out[((size_t)((d >> 4) * 32 + (by & 31))) * 512 + lane * 8] = v8;
        }
    } else if (bid < 4352) {
        const int o = bid - 3328;                      // wc1 chan
        const int i0 = tid * 4;
        const float* src = w1c + (size_t)o * 3072 + tid * 12;
        float4 v0 = *(const float4*)&src[0];
        float4 v1 = *(const float4*)&src[4];
        float4 v2 = *(const float4*)&src[8];
        const float f[12] = {v0.x, v0.y, v0.z, v0.w, v1.x, v1.y, v1.z, v1.w, v2.x, v2.y, v2.z, v2.w};
        const int ip = i0 & ~7;                        // even-thread i0
        const int lane = (o & 15) | (((ip >> 3) & 3) << 4);
        #pragma unroll
        for (int r = 0; r < 3; ++r) {
            bf16x4 o4;
            #pragma unroll
            for (int j = 0; j < 4; ++j) o4[j] = (bf16_t)f[j * 3 + r];
            bf16_t* ea = &wc1[((size_t)(r * 2048 + (o >> 4) * 32 + (ip >> 5))) * 512 + lane * 8];
            pair_store16(ea, o4, tid);
        }
    } else {
        const int rowmap[4] = {0, 129, 130, 259};
        const int f = tid * 16;
        const int r = f >> 10, w = f & 1023;
        bf16x8 z8 = (bf16x8)(bf16_t)0.0f;
        bf16_t* p0 = xp0 + (size_t)rowmap[r] * 1024 + w;
        bf16_t* p1 = xp1 + (size_t)rowmap[r] * 1024 + w;
        *(bf16x8*)p0 = z8; *(bf16x8*)(p0 + 8) = z8;
        *(bf16x8*)p1 = z8; *(bf16x8*)(p1 + 8) = z8;
        float4 wv = *(const float4*)&w2[tid * 4];
        f16x4 wo; wo[0] = (f16_t)wv.x; wo[1] = (f16_t)wv.y; wo[2] = (f16_t)wv.z; wo[3] = (f16_t)wv.w;
        *(f16x4*)&w2f[tid * 4] = wo;
    }
}

// ---------------------------------------------------------------------------
// helpers
// ---------------------------------------------------------------------------
__device__ __forceinline__ float wave_red_add(float v) {
    #pragma unroll
    for (int off = 32; off > 0; off >>= 1) v += __shfl_xor(v, off);
    return v;
}

// Conv MFMA body: weights fragment-packed (contiguous 1KB loads issued
// before LDS staging); activations staged in padded LDS [34][264].
__device__ __forceinline__ void conv_body(
    const bf16_t* __restrict__ WcP, const bf16_t* __restrict__ xp,
    int by, int b, int tbase, int w, int l, bf16_t* Bs, int tid,
    f32x4& acc0, f32x4& acc1)
{
    const int lm = l & 15, lk = (l >> 4) * 8;
    const bf16_t* xrow = xp + (size_t)(b * 130 + tbase) * 1024;
    #pragma unroll 1
    for (int c = 0; c < 4; ++c) {
        __syncthreads();
        const int kc = c * 8 + w;
        const bf16_t* a0 = WcP + ((size_t)(by * 32 + kc)) * 512 + l * 8;
        v4i A0, A1, A2;
        GLD(A0, a0, 0);
        GLD(A1, a0 + 1048576, 0);
        GLD(A2, a0 + 2097152, 0);
        for (int idx = tid; idx < 1088; idx += 512) {
            const int row = idx >> 5, col = (idx & 31) * 8;
            *(v4i*)&Bs[row * 264 + col] =
                *(const v4i*)&xrow[(size_t)row * 1024 + c * 256 + col];
        }
        __syncthreads();
        const int cb = w * 32 + lk;
        bf16x8 b00 = *(const bf16x8*)&Bs[(lm + 0) * 264 + cb];
        bf16x8 b10 = *(const bf16x8*)&Bs[(lm + 16) * 264 + cb];
        bf16x8 b01 = *(const bf16x8*)&Bs[(lm + 1) * 264 + cb];
        bf16x8 b11 = *(const bf16x8*)&Bs[(lm + 17) * 264 + cb];
        bf16x8 b02 = *(const bf16x8*)&Bs[(lm + 2) * 264 + cb];
        bf16x8 b12 = *(const bf16x8*)&Bs[(lm + 18) * 264 + cb];
        WAITV(2);
        acc0 = __builtin_amdgcn_mfma_f32_16x16x32_bf16(as_bf16x8(A0), b00, acc0, 0, 0, 0);
        acc1 = __builtin_amdgcn_mfma_f32_16x16x32_bf16(as_bf16x8(A0), b10, acc1, 0, 0, 0);
        WAITV(1);
        acc0 = __builtin_amdgcn_mfma_f32_16x16x32_bf16(as_bf16x8(A1), b01, acc0, 0, 0, 0);
        acc1 = __builtin_amdgcn_mfma_f32_16x16x32_bf16(as_bf16x8(A1), b11, acc1, 0, 0, 0);
        WAITV(0);
        acc0 = __builtin_amdgcn_mfma_f32_16x16x32_bf16(as_bf16x8(A2), b02, acc0, 0, 0, 0);
        acc1 = __builtin_amdgcn_mfma_f32_16x16x32_bf16(as_bf16x8(A2), b12, acc1, 0, 0, 0);
    }
    __syncthreads();
}

// ---------------------------------------------------------------------------
// P2: [0,512) conv1; [512,768) tp gemm; [768,1792) ap gemm;
//     [1792,2304) wc2 fragment-pack (2 chans/block) + Sg/Sb/SgF/SbF.
// ---------------------------------------------------------------------------
__global__ __launch_bounds__(512) void p2_k(
    const bf16_t* __restrict__ wc1, const bf16_t* __restrict__ xp0,
    const float* __restrict__ d_b1, bf16_t* __restrict__ xp1,
    float* __restrict__ bstat1,
    const bf16_t* __restrict__ textP, const bf16_t* __restrict__ topP,
    const float* __restrict__ a_b1, f16_t* __restrict__ tp,
    const bf16_t* __restrict__ audioP, const bf16_t* __restrict__ botP,
    f16_t* __restrict__ apT4,
    const float* __restrict__ w2c, const float* __restrict__ g1,
    const float* __restrict__ b1g, bf16_t* __restrict__ wc2,
    float* __restrict__ Sg3, float* __restrict__ Sb3,
    float* __restrict__ SgF, float* __restrict__ SbF)
{
    __shared__ float smem[8448];
    __shared__ float sred[8], sredq[8];
    const int bid = blockIdx.x;
    const int tid = threadIdx.x;
    const int w = tid >> 6, l = tid & 63;
    const int lm = l & 15, lh = l >> 4;
    if (bid < 512) {
        const int bx = bid >> 6, by = bid & 63;
        const int bt0 = bx * 32, m0 = by * 16;
        const int b = bt0 >> 7, tbase = bt0 & 127;
        f32x4 acc0 = (f32x4)(0.0f), acc1 = (f32x4)(0.0f);
        conv_body(wc1, xp0, by, b, tbase, w, l, (bf16_t*)smem, tid, acc0, acc1);
        float* sl = smem + w * 528;
        #pragma unroll
        for (int r = 0; r < 4; ++r) {
            sl[(lh * 4 + r) * 33 + lm] = acc0[r];
            sl[(lh * 4 + r) * 33 + 16 + lm] = acc1[r];
        }
        __syncthreads();
        const int mm = tid >> 5, nn = tid & 31;  // chan-local, bt-local
        float v = 0.f;
        #pragma unroll
        for (int ww = 0; ww < 8; ++ww) v += smem[ww * 528 + mm * 33 + nn];
        v = fmaxf(v + d_b1[m0 + mm], 0.f);
        float s = wave_red_add(v), q = wave_red_add(v * v);
        if (l == 0) { sred[w] = s; sredq[w] = q; }
        xp1[(size_t)(b * 130 + 1 + tbase + nn) * 1024 + m0 + mm] = (bf16_t)v;
        __syncthreads();
        if (tid == 0) {
            float ts = 0.f, tq = 0.f;
            #pragma unroll
            for (int ww = 0; ww < 8; ++ww) { ts += sred[ww]; tq += sredq[ww]; }
            bstat1[bid * 2] = ts; bstat1[bid * 2 + 1] = tq;
        }
    } else if (bid < 1792) {
        // gemm 32x32 tile, 8-way K-split; fragment-packed operands.
        const bf16_t *At, *Bm;
        int d0, r0, is_tp;
        if (bid < 768) {
            const int unit = bid - 512;          // 256 units: 8 bt x 32 d
            d0 = (unit & 31) * 32; r0 = (unit >> 5) * 32;
            At = topP; Bm = textP; is_tp = 1;
        } else {
            const int unit = bid - 768;          // 1024 units: 32 a x 32 d
            d0 = (unit & 31) * 32; r0 = (unit >> 5) * 32;
            At = botP; Bm = audioP; is_tp = 0;
        }
        const int rb0 = d0 >> 4, rbB = r0 >> 4;
        const bf16_t* Ap0 = At + ((size_t)(rb0 * 32 + w * 4)) * 512 + l * 8;
        const bf16_t* Ap1 = Ap0 + 16384;
        const bf16_t* Bp0 = Bm + ((size_t)(rbB * 32 + w * 4)) * 512 + l * 8;
        const bf16_t* Bp1 = Bp0 + 16384;
        v4i qa0[4], qa1[4], qb0[4], qb1[4];
        GLD(qa0[0], Ap0,    0); GLD(qa1[0], Ap1,    0); GLD(qb0[0], Bp0,    0); GLD(qb1[0], Bp1,    0);
        GLD(qa0[1], Ap0, 1024); GLD(qa1[1], Ap1, 1024); GLD(qb0[1], Bp0, 1024); GLD(qb1[1], Bp1, 1024);
        GLD(qa0[2], Ap0, 2048); GLD(qa1[2], Ap1, 2048); GLD(qb0[2], Bp0, 2048); GLD(qb1[2], Bp1, 2048);
        GLD(qa0[3], Ap0, 3072); GLD(qa1[3], Ap1, 3072); GLD(qb0[3], Bp0, 3072); GLD(qb1[3], Bp1, 3072);
        f32x4 acc[2][2];
        #pragma unroll
        for (int mt = 0; mt < 2; ++mt)
            #pragma unroll
            for (int nt = 0; nt < 2; ++nt) acc[mt][nt] = (f32x4)(0.0f);
#define GMF(cc, n) \
        WAITV(n); \
        acc[0][0] = __builtin_amdgcn_mfma_f32_16x16x32_bf16(as_bf16x8(qa0[cc]), as_bf16x8(qb0[cc]), acc[0][0], 0, 0, 0); \
        acc[0][1] = __builtin_amdgcn_mfma_f32_16x16x32_bf16(as_bf16x8(qa0[cc]), as_bf16x8(qb1[cc]), acc[0][1], 0, 0, 0); \
        acc[1][0] = __builtin_amdgcn_mfma_f32_16x16x32_bf16(as_bf16x8(qa1[cc]), as_bf16x8(qb0[cc]), acc[1][0], 0, 0, 0); \
        acc[1][1] = __builtin_amdgcn_mfma_f32_16x16x32_bf16(as_bf16x8(qa1[cc]), as_bf16x8(qb1[cc]), acc[1][1], 0, 0, 0)
        GMF(0, 12); GMF(1, 8); GMF(2, 4); GMF(3, 0);
#undef GMF
        float* sl = smem + w * 1056;
        #pragma unroll
        for (int mt = 0; mt < 2; ++mt)
            #pragma unroll
            for (int nt = 0; nt < 2; ++nt)
                #pragma unroll
                for (int r = 0; r < 4; ++r)
                    sl[(mt * 16 + lh * 4 + r) * 33 + nt * 16 + lm] = acc[mt][nt][r];
        __syncthreads();
        const int m = tid >> 4, n2 = (tid & 15) * 2;     // d-local, row-local pair
        float v0 = 0.f, v1 = 0.f;
        #pragma unroll
        for (int ww = 0; ww < 8; ++ww) {
            v0 += smem[ww * 1056 + m * 33 + n2];
            v1 += smem[ww * 1056 + m * 33 + n2 + 1];
        }
        if (is_tp) {
            const float bb = a_b1[d0 + m];
            tp[(size_t)(r0 + n2) * 1024 + d0 + m] = (f16_t)(v0 + bb);
            tp[(size_t)(r0 + n2 + 1) * 1024 + d0 + m] = (f16_t)(v1 + bb);
        } else {
            const int h = d0 + m, hq = h >> 2, hr = h & 3;
            const int a0 = r0 + n2;
            const int bbk = a0 >> 9, al = a0 & 511;
            apT4[((size_t)hq * 1024 + bbk * 512 + al) * 4 + hr] = (f16_t)v0;
            apT4[((size_t)hq * 1024 + bbk * 512 + al + 1) * 4 + hr] = (f16_t)v1;
        }
    } else {
        // ---- wc2 fragment-pack + Sg/Sb/SgF/SbF (2 chans/block) ----------
        const int half = tid >> 8, t = tid & 255;
        const int o = (bid - 1792) * 2 + half;
        const int i0 = t * 4;
        const float* src = w2c + (size_t)o * 3072 + t * 12;
        float4 v0 = *(const float4*)&src[0];
        float4 v1 = *(const float4*)&src[4];
        float4 v2 = *(const float4*)&src[8];
        const float f[12] = {v0.x, v0.y, v0.z, v0.w, v1.x, v1.y, v1.z, v1.w, v2.x, v2.y, v2.z, v2.w};
        float4 gv = *(const float4*)&g1[i0];
        float4 bv = *(const float4*)&b1g[i0];
        const float g4[4] = {gv.x, gv.y, gv.z, gv.w};
        const float bb4[4] = {bv.x, bv.y, bv.z, bv.w};
        const int ip = i0 & ~7;
        const int lane = (o & 15) | (((ip >> 3) & 3) << 4);
        float sgr[3] = {0.f, 0.f, 0.f}, sbr[3] = {0.f, 0.f, 0.f};
        #pragma unroll
        for (int r = 0; r < 3; ++r) {
            bf16x4 o4;
            #pragma unroll
            for (int j = 0; j < 4; ++j) {
                const float wv = f[j * 3 + r];
                const float ws = wv * g4[j];
                sgr[r] += ws;
                sbr[r] += wv * bb4[j];
                o4[j] = (bf16_t)ws;
            }
            bf16_t* ea = &wc2[((size_t)(r * 2048 + (o >> 4) * 32 + (ip >> 5))) * 512 + lane * 8];
            pair_store16(ea, o4, t);
        }
        #pragma unroll
        for (int off = 32; off > 0; off >>= 1) {
            #pragma unroll
            for (int r = 0; r < 3; ++r) {
                sgr[r] += __shfl_xor(sgr[r], off);
                sbr[r] += __shfl_xor(sbr[r], off);
            }
        }
        float* red = smem + half * 32;
        const int wid = t >> 6, lane2 = t & 63;
        if (lane2 == 0) {
            #pragma unroll
            for (int r = 0; r < 3; ++r) {
                red[wid * 6 + r] = sgr[r];
                red[wid * 6 + 3 + r] = sbr[r];
            }
        }
        __syncthreads();
        if (t < 6) {
            const float v = red[t] + red[6 + t] + red[12 + t] + red[18 + t];
            if (t < 3) Sg3[o * 3 + t] = v;
            else       Sb3[o * 3 + t - 3] = v;
            red[24 + t] = v;
        }
        __syncthreads();
        if (t == 0)      SgF[o] = red[24] + red[25] + red[26];
        else if (t == 1) SbF[o] = red[27] + red[28] + red[29];
    }
}

// reduce 256 (s,q) pairs for batch b from bstat (block-level, 512 threads).
__device__ __forceinline__ void reduce_bstat(
    const float* __restrict__ bstat, int b, int tid,
    float* sr, float* sq, float& mu, float& rsig)
{
    const int lane = tid & 63, wid = tid >> 6;
    float s = 0.f, q = 0.f;
    if (tid < 256) {
        float2 v = ((const float2*)bstat)[b * 256 + tid];
        s = v.x; q = v.y;
    }
    #pragma unroll
    for (int off = 32; off > 0; off >>= 1) {
        s += __shfl_xor(s, off);
        q += __shfl_xor(q, off);
    }
    if (lane == 0) { sr[wid] = s; sq[wid] = q; }
    __syncthreads();
    float ts = 0.f, tq = 0.f;
    #pragma unroll
    for (int i = 0; i < 8; ++i) { ts += sr[i]; tq += sq[i]; }
    const float cnt = 131072.f;
    mu = ts / cnt;
    const float var = tq / cnt - mu * mu;
    rsig = rsqrtf(var + EPSV);
}

// ---------------------------------------------------------------------------
// P3: blocks [0,512) conv2 tiles (GN1 folded); [512,768) logits blocks.
// ---------------------------------------------------------------------------
__device__ __forceinline__ float dot2_acc(f16x2 x, f16x2 w, float acc) {
#if __has_builtin(__builtin_amdgcn_fdot2)
    return __builtin_amdgcn_fdot2(x, w, acc, false);
#else
    return acc + (float)x[0] * (float)w[0] + (float)x[1] * (float)w[1];
#endif
}

__global__ __launch_bounds__(512) void p3_k(
    const bf16_t* __restrict__ wc2, const bf16_t* __restrict__ xp1,
    const float* __restrict__ d_b2, bf16_t* __restrict__ y2,
    float* __restrict__ bstat2, const float* __restrict__ bstat1,
    const float* __restrict__ SgF, const float* __restrict__ SbF,
    const float* __restrict__ Sg3, const float* __restrict__ Sb3,
    const f16_t* __restrict__ tp, const f16_t* __restrict__ apT4,
    const f16_t* __restrict__ w2f, float* __restrict__ lp)
{
    __shared__ float smem[4608];                 // conv: Bs bf16[34][264] then [8][16][33]
    __shared__ float sred[8], sredq[8], sr[8], sq[8];
    const int bid = blockIdx.x;
    const int tid = threadIdx.x;
    if (bid < 512) {
        const int w = tid >> 6, l = tid & 63;
        const int lm = l & 15, lh = l >> 4;
        const int bx = bid >> 6, by = bid & 63;
        const int bt0 = bx * 32, m0 = by * 16;
        const int b = bt0 >> 7, tbase = bt0 & 127;
        f32x4 acc0 = (f32x4)(0.0f), acc1 = (f32x4)(0.0f);
        conv_body(wc2, xp1, by, b, tbase, w, l, (bf16_t*)smem, tid, acc0, acc1);
        float* sl = smem + w * 528;
        #pragma unroll
        for (int r = 0; r < 4; ++r) {
            sl[(lh * 4 + r) * 33 + lm] = acc0[r];
            sl[(lh * 4 + r) * 33 + 16 + lm] = acc1[r];
        }
        __syncthreads();
        const int mm = tid >> 5, nn = tid & 31;
        float vraw = 0.f;
        #pragma unroll
        for (int ww = 0; ww < 8; ++ww) vraw += smem[ww * 528 + mm * 33 + nn];
        float mu, rsig;
        reduce_bstat(bstat1, b, tid, sr, sq, mu, rsig);   // has its own barrier
        const int o = m0 + mm, tloc = tbase + nn;
        float sg = SgF[o], sb = SbF[o];
        if (tloc == 0)   { sg -= Sg3[o * 3];     sb -= Sb3[o * 3]; }
        if (tloc == 127) { sg -= Sg3[o * 3 + 2]; sb -= Sb3[o * 3 + 2]; }
        float v = fmaxf(rsig * vraw + sb - mu * rsig * sg + d_b2[o], 0.f);
        float s = wave_red_add(v), q = wave_red_add(v * v);
        if ((tid & 63) == 0) { sred[tid >> 6] = s; sredq[tid >> 6] = q; }
        y2[(size_t)(b * 128 + tloc) * 1024 + o] = (bf16_t)v;
        __syncthreads();
        if (tid == 0) {
            float ts = 0.f, tq = 0.f;
            #pragma unroll
            for (int ww = 0; ww < 8; ++ww) { ts += sred[ww]; tq += sredq[ww]; }
            bstat2[bid * 2] = ts; bstat2[bid * 2 + 1] = tq;
        }
    } else {
        const int lb = bid - 512;                       // 256 blocks
        const int hc = lb >> 6, btp = lb & 63;
        const int bt0 = btp * 4;
        const int b = bt0 >> 7;
        const int a = tid;                              // 0..511
        const f16_t* tpr = tp + (size_t)bt0 * 1024 + hc * 256;   // wave-uniform
        const f16_t* w2r = w2f + hc * 256;
        const f16_t* apc = apT4 + ((size_t)(hc * 64) * 1024 + b * 512 + a) * 4;
        float acc[4] = {0.f, 0.f, 0.f, 0.f};
        const f16x2 zero = (f16x2)(f16_t)0.0f;
#define L_A0(i) (*(const f16x4*)(apc + (size_t)(2 * (i)) * 4096))
#define L_A1(i) (*(const f16x4*)(apc + (size_t)(2 * (i) + 1) * 4096))
        constexpr int PF = 4;
        f16x4 pa[PF], pb[PF];
        #pragma unroll
        for (int i = 0; i < PF; ++i) { pa[i] = L_A0(i); pb[i] = L_A1(i); }
        #pragma unroll
        for (int i = 0; i < 32; ++i) {                  // hq pair per iter
            const int sl = i % PF;
            const int hq = 2 * i;
            f16x4 a0 = pa[sl], a1 = pb[sl];
            f16x4 w0 = *(const f16x4*)&w2r[hq * 4];
            f16x4 w1 = *(const f16x4*)&w2r[hq * 4 + 4];
            #pragma unroll
            for (int r = 0; r < 4; ++r) {
                f16x4 t0 = *(const f16x4*)&tpr[r * 1024 + hq * 4];
                f16x4 t1 = *(const f16x4*)&tpr[r * 1024 + hq * 4 + 4];
                f16x2 p;
                p = __builtin_elementwise_max((f16x2){t0[0] + a0[0], t0[1] + a0[1]}, zero);
                acc[r] = dot2_acc(p, (f16x2){w0[0], w0[1]}, acc[r]);
                p = __builtin_elementwise_max((f16x2){t0[2] + a0[2], t0[3] + a0[3]}, zero);
                acc[r] = dot2_acc(p, (f16x2){w0[2], w0[3]}, acc[r]);
                p = __builtin_elementwise_max((f16x2){t1[0] + a1[0], t1[1] + a1[1]}, zero);
                acc[r] = dot2_acc(p, (f16x2){w1[0], w1[1]}, acc[r]);
                p = __builtin_elementwise_max((f16x2){t1[2] + a1[2], t1[3] + a1[3]}, zero);
                acc[r] = dot2_acc(p, (f16x2){w1[2], w1[3]}, acc[r]);
            }
            const int nx = i + PF;
            if (nx < 32) { pa[sl] = L_A0(nx); pb[sl] = L_A1(nx); }
        }
#undef L_A0
#undef L_A1
        float* dst = lp + (size_t)(hc * 256 + bt0) * 512 + a;
        #pragma unroll
        for (int r = 0; r < 4; ++r) dst[(size_t)r * 512] = acc[r];
    }
}

// ---------------------------------------------------------------------------
// combine: blocks [0,256): softmax; [256,288): conv3 + GN2 + softplus.
// ---------------------------------------------------------------------------
__global__ __launch_bounds__(512) void combine_k(
    const float* __restrict__ lp, const float* __restrict__ b2,
    const bf16_t* __restrict__ y2, const float* __restrict__ bstat2,
    const float* __restrict__ g, const float* __restrict__ bet,
    const float* __restrict__ w3, const float* __restrict__ b3,
    float* __restrict__ out)
{
    __shared__ float redm[8], redsum[8];
    const int bid = blockIdx.x;
    const int tid = threadIdx.x;
    if (bid < 256) {
        const int bt = bid, t = bt & 127;
        const int a = tid;
        const int lane = a & 63, wid = a >> 6;
        const size_t base = (size_t)bt * 512 + a;
        float v = lp[base] + lp[131072 + base] + lp[262144 + base] + lp[393216 + base];
        v += b2[0] - 0.1f * fabsf((float)a - 4.0f * (float)t);
        float m = v;
        #pragma unroll
        for (int off = 32; off > 0; off >>= 1) m = fmaxf(m, __shfl_xor(m, off));
        if (lane == 0) redm[wid] = m;
        __syncthreads();
        float M = redm[0];
        #pragma unroll
        for (int i = 1; i < 8; ++i) M = fmaxf(M, redm[i]);
        const float e = expf(v - M);
        float s = e;
        #pragma unroll
        for (int off = 32; off > 0; off >>= 1) s += __shfl_xor(s, off);
        if (lane == 0) redsum[wid] = s;
        __syncthreads();
        float S = redsum[0];
        #pragma unroll
        for (int i = 1; i < 8; ++i) S += redsum[i];
        out[(size_t)bt * 512 + a] = e * (1.0f / S);
    } else {
        const int cb = bid - 256;              // 0..31, bt [cb*8, cb*8+8)
        const int b = (cb * 8) >> 7;
        float mu, rsig;
        reduce_bstat(bstat2, b, tid, redm, redsum, mu, rsig);
        const int lane = tid & 63, w = tid >> 6;
        const int bt = cb * 8 + w;
        const bf16_t* row = y2 + (size_t)bt * 1024 + lane * 16;
        float s1 = 0.f, s2 = 0.f, s3 = 0.f;
        #pragma unroll
        for (int c = 0; c < 2; ++c) {
            bf16x8 yv = *(const bf16x8*)(row + c * 8);
            #pragma unroll
            for (int j = 0; j < 8; ++j) {
                const int i = lane * 16 + c * 8 + j;
                const float gw = g[i] * w3[i];
                s1 += gw * (float)yv[j];
                s2 += gw;
                s3 += bet[i] * w3[i];
            }
        }
        #pragma unroll
        for (int off = 32; off > 0; off >>= 1) {
            s1 += __shfl_xor(s1, off);
            s2 += __shfl_xor(s2, off);
            s3 += __shfl_xor(s3, off);
        }
        if (lane == 0) {
            const float t = rsig * (s1 - mu * s2) + s3 + b3[0];
            out[131072 + bt] = fmaxf(t, 0.f) + log1pf(expf(-fabsf(t)));
        }
    }
}

extern "C" void kernel_launch(void* const* d_in, const int* in_sizes, int n_in,
                              void* d_out, int out_size, void* d_ws, size_t ws_size,
                              hipStream_t stream) {
    const float* text   = (const float*)d_in[0];
    const float* audio  = (const float*)d_in[1];
    const float* a_w1   = (const float*)d_in[2];
    const float* a_b1   = (const float*)d_in[3];
    const float* a_w2   = (const float*)d_in[4];
    const float* a_b2   = (const float*)d_in[5];
    const float* d_w1   = (const float*)d_in[6];
    const float* d_b1   = (const float*)d_in[7];
    const float* gn1_g  = (const float*)d_in[8];
    const float* gn1_b  = (const float*)d_in[9];
    const float* d_w2   = (const float*)d_in[10];
    const float* d_b2   = (const float*)d_in[11];
    const float* gn2_g  = (const float*)d_in[12];
    const float* gn2_b  = (const float*)d_in[13];
    const float* d_w3   = (const float*)d_in[14];
    const float* d_b3   = (const float*)d_in[15];

    char* ws = (char*)d_ws;
    float* outf = (float*)d_out;

    bf16_t* textP    = (bf16_t*)(ws + OFF_TEXTP);
    bf16_t* audioP   = (bf16_t*)(ws + OFF_AUDIOP);
    bf16_t* topP     = (bf16_t*)(ws + OFF_W1TOP);
    bf16_t* botP     = (bf16_t*)(ws + OFF_W1BOT);
    bf16_t* wc1      = (bf16_t*)(ws + OFF_WC1);
    bf16_t* wc2      = (bf16_t*)(ws + OFF_WC2);
    f16_t*  tp       = (f16_t*) (ws + OFF_TP);
    f16_t*  w2f      = (f16_t*) (ws + OFF_W2F);
    f16_t*  apT4     = (f16_t*) (ws + OFF_APT);
    bf16_t* xp0      = (bf16_t*)(ws + OFF_XP0);
    bf16_t* xp1      = (bf16_t*)(ws + OFF_XP1);
    bf16_t* y2       = (bf16_t*)(ws + OFF_Y2);
    float*  bstat1   = (float*) (ws + OFF_BST1);
    float*  bstat2   = (float*) (ws + OFF_BST2);
    float*  lp       = (float*) (ws + OFF_LP);
    float*  Sg3      = (float*) (ws + OFF_SG);
    float*  Sb3      = (float*) (ws + OFF_SB);
    float*  SgFp     = (float*) (ws + OFF_SGF);
    float*  SbFp     = (float*) (ws + OFF_SBF);

    // 1: prep (act pack, w1 pack, wc1 pack, pads, w2f)
    prep_k<<<dim3(4353), 256, 0, stream>>>(text, audio, a_w1, d_w1, a_w2,
                                           textP, xp0, audioP, topP, botP,
                                           wc1, xp1, w2f);
    // 2: conv1 (512) ∥ tp gemm (256) ∥ ap gemm (1024) ∥ wc2-pack (512)
    p2_k<<<dim3(2304), 512, 0, stream>>>(wc1, xp0, d_b1, xp1, bstat1,
                                         textP, topP, a_b1, tp,
                                         audioP, botP, apT4,
                                         d_w2, gn1_g, gn1_b, wc2,
                                         Sg3, Sb3, SgFp, SbFp);
    // 3: conv2 (512, GN1 folded) ∥ logits (256) — 768 x 512 thr
    p3_k<<<dim3(768), 512, 0, stream>>>(wc2, xp1, d_b2, y2, bstat2, bstat1,
                                        SgFp, SbFp, Sg3, Sb3, tp, apT4, w2f, lp);
    // 4: combine+softmax -> alignment; conv3+GN2(reduced)+softplus -> durations
    combine_k<<<dim3(288), 512, 0, stream>>>(lp, a_b2, y2, bstat2,
                                             gn2_g, gn2_b, d_w3, d_b3, outf);
}